// Round 8
// baseline (2275.929 us; speedup 1.0000x reference)
//
#include <hip/hip_runtime.h>
#include <hip/hip_bf16.h>

// MultiVForecaster: 4-layer Mamba (B=16, L=1024, D=512, ED=1024, N=16).
// Round 8: 256x256 2-phase MFMA GEMM (512 thr, 8 waves, BK=64, 128KB LDS)
// for in_proj / fused delta+BC / out_proj. Scan & elementwise unchanged.

#define B_ 16
#define L_ 1024
#define D_ 512
#define ED_ 1024
#define N_ 16
#define DR_ 32
#define DC_ 4
#define BL_ (B_ * L_)

typedef __attribute__((ext_vector_type(8))) __bf16 bf16x8;
typedef __attribute__((ext_vector_type(4))) float f32x4;

#define ASYNC_LDS16(G, L)                                                      \
  __builtin_amdgcn_global_load_lds(                                            \
      (const __attribute__((address_space(1))) void*)(G),                      \
      (__attribute__((address_space(3))) void*)(L), 16, 0, 0)

__device__ __forceinline__ float bf2f(unsigned short v) {
  unsigned int u = (unsigned int)v << 16;
  return __builtin_bit_cast(float, u);
}

// ---------------------------------------------------------------- embed
__global__ __launch_bounds__(256) void embed_kernel(
    const float* __restrict__ x, const float* __restrict__ w,
    const float* __restrict__ bias, float* __restrict__ h) {
  __shared__ float xs[64][36];
  __shared__ float ws[32][513];
  const int tid = threadIdx.x;
  const int b = blockIdx.y, l0 = blockIdx.x * 64;
  for (int f = tid; f < 16384; f += 256) {
    int d = f >> 5, i = f & 31;
    ws[i][d] = w[f];
  }
  for (int f = tid; f < 2048; f += 256) {
    int i = f >> 6, l = f & 63;
    xs[l][i] = x[b * 32768 + i * 1024 + l0 + l];
  }
  const int d0 = tid, d1 = tid + 256;
  __syncthreads();
  float wr0[32], wr1[32];
#pragma unroll
  for (int i = 0; i < 32; ++i) {
    wr0[i] = ws[i][d0];
    wr1[i] = ws[i][d1];
  }
  const float b0 = bias[d0], b1 = bias[d1];
  for (int l = 0; l < 64; ++l) {
    float a0 = b0, a1 = b1;
#pragma unroll
    for (int q = 0; q < 8; ++q) {
      float4 xv = *(float4*)&xs[l][q * 4];
      a0 = fmaf(xv.x, wr0[q * 4], a0);
      a1 = fmaf(xv.x, wr1[q * 4], a1);
      a0 = fmaf(xv.y, wr0[q * 4 + 1], a0);
      a1 = fmaf(xv.y, wr1[q * 4 + 1], a1);
      a0 = fmaf(xv.z, wr0[q * 4 + 2], a0);
      a1 = fmaf(xv.z, wr1[q * 4 + 2], a1);
      a0 = fmaf(xv.w, wr0[q * 4 + 3], a0);
      a1 = fmaf(xv.w, wr1[q * 4 + 3], a1);
    }
    size_t row = (size_t)(b << 10) + l0 + l;
    h[row * 512 + d0] = a0;
    h[row * 512 + d1] = a1;
  }
}

// ---------------------------------------------------------------- cvt f32->bf16
__global__ __launch_bounds__(256) void cvt_bf16_kernel(
    const float* __restrict__ src, __hip_bfloat16* __restrict__ dst, int n4) {
  int i = blockIdx.x * 256 + threadIdx.x;
  if (i < n4) {
    float4 v = *(const float4*)&src[(size_t)i * 4];
    __hip_bfloat16 t4[4] = {__float2bfloat16(v.x), __float2bfloat16(v.y),
                            __float2bfloat16(v.z), __float2bfloat16(v.w)};
    *(ushort4*)&dst[(size_t)i * 4] = *(ushort4*)t4;
  }
}

// wxpT[i][k,r] = x_proj_w[i][r,k], r<32 (dt_rank rows)
__global__ __launch_bounds__(256) void transpose_xp_kernel(
    const float* __restrict__ xp, __hip_bfloat16* __restrict__ xpT) {
  int t = blockIdx.x * 256 + threadIdx.x;
  int r = t & 31, k = (t >> 5) & 1023, i = t >> 15;
  xpT[i * 32768 + k * 32 + r] = __float2bfloat16(xp[i * 65536 + r * 1024 + k]);
}

// wcat rows 1024..1279: [1024..1055] = xp rows 32..63 (B,C); rest zero pad.
__global__ __launch_bounds__(256) void wcat_tail_kernel(
    const float* __restrict__ xp, __hip_bfloat16* __restrict__ wcat) {
  int t = blockIdx.x * 256 + threadIdx.x;  // 4 * 256 * 1024
  int k = t & 1023, row = (t >> 10) & 255, i = t >> 18;
  float v = (row < 32) ? xp[i * 65536 + (32 + row) * 1024 + k] : 0.f;
  wcat[(size_t)i * 1310720 + (size_t)(1024 + row) * 1024 + k] =
      __float2bfloat16(v);
}

// ---------------------------------------------------------------- rmsnorm
__global__ __launch_bounds__(256) void rmsnorm_kernel(
    const float* __restrict__ h, const float* __restrict__ w,
    __hip_bfloat16* __restrict__ hn) {
  const int tid = threadIdx.x;
  const int row = blockIdx.x * 2 + (tid >> 7);
  const int t = tid & 127;
  float4 v = *(const float4*)&h[(size_t)row * 512 + t * 4];
  float ss = v.x * v.x + v.y * v.y + v.z * v.z + v.w * v.w;
#pragma unroll
  for (int o = 32; o; o >>= 1) ss += __shfl_down(ss, o);
  __shared__ float red[2][2];
  if ((tid & 63) == 0) red[tid >> 7][(tid >> 6) & 1] = ss;
  __syncthreads();
  float tot = red[tid >> 7][0] + red[tid >> 7][1];
  float scale = rsqrtf(tot * (1.f / D_) + 1e-5f);
  float4 wv = *(const float4*)&w[t * 4];
  __hip_bfloat16 t4[4] = {__float2bfloat16(v.x * scale * wv.x),
                          __float2bfloat16(v.y * scale * wv.y),
                          __float2bfloat16(v.z * scale * wv.z),
                          __float2bfloat16(v.w * scale * wv.w)};
  *(ushort4*)&hn[(size_t)row * 512 + t * 4] = *(ushort4*)t4;
}

// ---------------------------------------------------------------- small MFMA GEMM (wcomb only)
// 128x128 tile, 4 waves, BK=32. EPI 6: bf16 store auxb (ldc).
__global__ __launch_bounds__(256) void gemm_mfma_kernel(
    const __hip_bfloat16* __restrict__ A, int lda,
    const __hip_bfloat16* __restrict__ W, __hip_bfloat16* __restrict__ auxb,
    int ldc, int K) {
  __shared__ __bf16 As[2][4096];
  __shared__ __bf16 Bs[2][4096];
  const int tid = threadIdx.x;
  const int w = tid >> 6, l = tid & 63;
  const int m0 = blockIdx.y * 128, n0 = blockIdx.x * 128;
  const int wr = w >> 1, wc = w & 1;
  const int lrow = l & 15, lk = (l >> 4) * 8;
  const size_t arow0 = (size_t)(m0 + w * 16 + lrow) * lda + lk;
  const size_t arow1 = (size_t)(m0 + (w + 4) * 16 + lrow) * lda + lk;
  const size_t brow0 = (size_t)(n0 + w * 16 + lrow) * K + lk;
  const size_t brow1 = (size_t)(n0 + (w + 4) * 16 + lrow) * K + lk;

  f32x4 acc[4][4];
#pragma unroll
  for (int i = 0; i < 4; ++i)
#pragma unroll
    for (int j = 0; j < 4; ++j) acc[i][j] = (f32x4)0.f;

  auto stage = [&](int bufi, int k0) {
    ASYNC_LDS16(A + arow0 + k0, &As[bufi][w * 512]);
    ASYNC_LDS16(A + arow1 + k0, &As[bufi][(w + 4) * 512]);
    ASYNC_LDS16(W + brow0 + k0, &Bs[bufi][w * 512]);
    ASYNC_LDS16(W + brow1 + k0, &Bs[bufi][(w + 4) * 512]);
  };

  stage(0, 0);
  int buf = 0;
  for (int k0 = 0; k0 < K; k0 += 32) {
    __syncthreads();
    if (k0 + 32 < K) stage(buf ^ 1, k0 + 32);
    bf16x8 af[4], bfr[4];
#pragma unroll
    for (int mi = 0; mi < 4; ++mi)
      af[mi] = *(bf16x8*)&As[buf][(wr * 4 + mi) * 512 + l * 8];
#pragma unroll
    for (int ni = 0; ni < 4; ++ni)
      bfr[ni] = *(bf16x8*)&Bs[buf][(wc * 4 + ni) * 512 + l * 8];
#pragma unroll
    for (int mi = 0; mi < 4; ++mi)
#pragma unroll
      for (int ni = 0; ni < 4; ++ni)
        acc[mi][ni] = __builtin_amdgcn_mfma_f32_16x16x32_bf16(
            af[mi], bfr[ni], acc[mi][ni], 0, 0, 0);
    buf ^= 1;
  }
#pragma unroll
  for (int mi = 0; mi < 4; ++mi)
#pragma unroll
    for (int ni = 0; ni < 4; ++ni) {
      int row0 = m0 + (wr * 4 + mi) * 16 + (l >> 4) * 4;
      int col = n0 + (wc * 4 + ni) * 16 + (l & 15);
#pragma unroll
      for (int r2 = 0; r2 < 4; ++r2)
        auxb[(size_t)(row0 + r2) * ldc + col] = __float2bfloat16(acc[mi][ni][r2]);
    }
}

// ---------------------------------------------------------------- 256x256 2-phase GEMM
// C[m,n] = sum_k A[m,k]*W[n,k]; bf16 K-contiguous. 512 threads = 8 waves
// (2 M x 4 N), per-wave 128x64 out (8 x FN frags of 16x16x32), BK=64.
// LDS fragment-ordered (frag slot = rowfrag*2+khalf, 512 bf16, lane l ->
// row l&15, k (l>>4)*8): conflict-free ds_read_b128, linear gload_lds dest.
// EPI: 1 f32 += | 5 bf16 split: col<1024->auxb raw, col>=1024->auxb2=silu |
//      8 col<1024 softplus(v+bias)->auxb bf16; 1024<=col<1056 -> f32 C[row*32+..]
template <int BN, int EPI>
__global__ __launch_bounds__(512) void gemm256_kernel(
    const __hip_bfloat16* __restrict__ A, int lda,
    const __hip_bfloat16* __restrict__ W, float* __restrict__ C, int ldc,
    __hip_bfloat16* __restrict__ auxb, __hip_bfloat16* __restrict__ auxb2,
    const float* __restrict__ bias, int K) {
  constexpr int FN = BN / 64;  // n-frags per wave (4 | 2) == B slots per wave
  __shared__ __bf16 As[2][256 * 64];
  __shared__ __bf16 Bs[2][BN * 64];
  const int tid = threadIdx.x;
  const int w = tid >> 6, l = tid & 63;
  const int wm = w >> 2, wn = w & 3;
  // bijective XCD swizzle
  const int gx = gridDim.x;
  const int nwg = gx * gridDim.y;
  const int wg = blockIdx.y * gx + blockIdx.x;
  const int q = nwg >> 3, r = nwg & 7;
  const int xcd = wg & 7, pos = wg >> 3;
  const int wgid =
      (xcd < r ? xcd * (q + 1) : r * (q + 1) + (xcd - r) * q) + pos;
  const int m0 = (wgid / gx) * 256, n0 = (wgid % gx) * BN;
  const int lrow = l & 15, lk = (l >> 4) * 8;

  unsigned int aoff[4], boff[FN];
#pragma unroll
  for (int i = 0; i < 4; ++i) {
    int s = w * 4 + i;  // A slot: rowfrag s>>1, khalf s&1
    aoff[i] = (unsigned)(m0 + (s >> 1) * 16 + lrow) * lda + (s & 1) * 32 + lk;
  }
#pragma unroll
  for (int i = 0; i < FN; ++i) {
    int s = w * FN + i;
    boff[i] = (unsigned)(n0 + (s >> 1) * 16 + lrow) * K + (s & 1) * 32 + lk;
  }

  f32x4 acc[8][FN];
#pragma unroll
  for (int mi = 0; mi < 8; ++mi)
#pragma unroll
    for (int ni = 0; ni < FN; ++ni) acc[mi][ni] = (f32x4)0.f;

  auto stage = [&](int bufi, int k0) {
#pragma unroll
    for (int i = 0; i < 4; ++i)
      ASYNC_LDS16(A + aoff[i] + k0, &As[bufi][(w * 4 + i) * 512]);
#pragma unroll
    for (int i = 0; i < FN; ++i)
      ASYNC_LDS16(W + boff[i] + k0, &Bs[bufi][(w * FN + i) * 512]);
  };

  stage(0, 0);
  int buf = 0;
  for (int k0 = 0; k0 < K; k0 += 64) {
    __syncthreads();
    if (k0 + 64 < K) stage(buf ^ 1, k0 + 64);
#pragma unroll
    for (int kk = 0; kk < 2; ++kk) {
      bf16x8 bfr[FN];
#pragma unroll
      for (int ni = 0; ni < FN; ++ni)
        bfr[ni] =
            *(bf16x8*)&Bs[buf][(((wn * FN + ni) << 1) + kk) * 512 + l * 8];
#pragma unroll
      for (int mi = 0; mi < 8; ++mi) {
        bf16x8 af = *(bf16x8*)&As[buf][(((wm * 8 + mi) << 1) + kk) * 512 + l * 8];
#pragma unroll
        for (int ni = 0; ni < FN; ++ni)
          acc[mi][ni] = __builtin_amdgcn_mfma_f32_16x16x32_bf16(
              af, bfr[ni], acc[mi][ni], 0, 0, 0);
      }
    }
    buf ^= 1;
  }

#pragma unroll
  for (int mi = 0; mi < 8; ++mi) {
#pragma unroll
    for (int ni = 0; ni < FN; ++ni) {
      int row0 = m0 + wm * 128 + mi * 16 + (l >> 4) * 4;
      int col = n0 + wn * (FN * 16) + ni * 16 + (l & 15);
#pragma unroll
      for (int r2 = 0; r2 < 4; ++r2) {
        int row = row0 + r2;
        float v = acc[mi][ni][r2];
        if (EPI == 1) {
          C[(size_t)row * ldc + col] += v;
        } else if (EPI == 5) {
          if (col < 1024) {
            auxb[(size_t)row * 1024 + col] = __float2bfloat16(v);
          } else {
            float g = v / (1.f + __expf(-v));
            auxb2[(size_t)row * 1024 + (col - 1024)] = __float2bfloat16(g);
          }
        } else if (EPI == 8) {
          if (col < 1024) {
            v += bias[col];
            v = (v > 20.f) ? v : log1pf(__expf(v));
            auxb[(size_t)row * 1024 + col] = __float2bfloat16(v);
          } else if (col < 1056) {
            C[(size_t)row * 32 + (col - 1024)] = v;
          }
        }
      }
    }
  }
}

// ---------------------------------------------------------------- conv+silu
__global__ __launch_bounds__(256) void conv_silu_kernel(
    const __hip_bfloat16* __restrict__ xcb, const float* __restrict__ cw,
    const float* __restrict__ cb, __hip_bfloat16* __restrict__ out) {
  int i = blockIdx.x * 256 + threadIdx.x;
  int ed = (i & 127) * 8;
  int bl = i >> 7;
  int l = bl & 1023;
  float4 cwv[8];
#pragma unroll
  for (int e = 0; e < 8; ++e) cwv[e] = *(const float4*)&cw[(ed + e) * 4];
  float ac[8];
  {
    float4 c0 = *(const float4*)&cb[ed];
    float4 c1 = *(const float4*)&cb[ed + 4];
    ac[0] = c0.x; ac[1] = c0.y; ac[2] = c0.z; ac[3] = c0.w;
    ac[4] = c1.x; ac[5] = c1.y; ac[6] = c1.z; ac[7] = c1.w;
  }
#pragma unroll
  for (int j = 0; j < DC_; ++j) {
    if (l - 3 + j >= 0) {
      const __hip_bfloat16* src = &xcb[(size_t)(bl - 3 + j) * 1024 + ed];
      ushort4 a = *(const ushort4*)src;
      ushort4 b = *(const ushort4*)(src + 4);
      unsigned short xv[8] = {a.x, a.y, a.z, a.w, b.x, b.y, b.z, b.w};
#pragma unroll
      for (int e = 0; e < 8; ++e)
        ac[e] = fmaf(bf2f(xv[e]), ((const float*)&cwv[e])[j], ac[e]);
    }
  }
  __hip_bfloat16 t8[8];
#pragma unroll
  for (int e = 0; e < 8; ++e) {
    float v = ac[e] / (1.f + __expf(-ac[e]));
    t8[e] = __float2bfloat16(v);
  }
  *(ushort4*)&out[(size_t)bl * 1024 + ed] = *(ushort4*)&t8[0];
  *(ushort4*)&out[(size_t)bl * 1024 + ed + 4] = *(ushort4*)&t8[4];
}

// ---------------------------------------------------------------- scan p1
__global__ __launch_bounds__(256) void scan_p1_kernel(
    const unsigned short* __restrict__ dlt, const float* __restrict__ dbc,
    const unsigned short* __restrict__ xc, const float* __restrict__ A_log,
    float* __restrict__ S, float* __restrict__ totd) {
  const int tid = threadIdx.x;
  const int ed = blockIdx.x * 256 + tid;
  const int c = blockIdx.y, b = blockIdx.z;
  const size_t row0 = ((size_t)b << 10) + c * 64;
  __shared__ float sB[64][16];
  {
    const int w = tid >> 6, l = tid & 63;
    ASYNC_LDS16(&dbc[(row0 + w * 16 + (l >> 2)) * 32 + (l & 3) * 4],
                &sB[w * 16][0]);
  }
  float An[16], h[16];
#pragma unroll
  for (int n = 0; n < 16; n += 4) {
    float4 a = *(const float4*)&A_log[ed * 16 + n];
    An[n] = -__expf(a.x);
    An[n + 1] = -__expf(a.y);
    An[n + 2] = -__expf(a.z);
    An[n + 3] = -__expf(a.w);
    h[n] = h[n + 1] = h[n + 2] = h[n + 3] = 0.f;
  }
  float cd = 0.f;
  size_t gi = row0 * 1024 + ed;
  __syncthreads();
  unsigned short nd = dlt[gi], nu = xc[gi];
#pragma unroll 4
  for (int t = 0; t < 64; ++t) {
    float dv = bf2f(nd), u = bf2f(nu);
    if (t < 63) {
      nd = dlt[gi + 1024];
      nu = xc[gi + 1024];
    }
    float du = dv * u;
    cd += dv;
    float Bv[16];
    *(float4*)&Bv[0] = *(float4*)&sB[t][0];
    *(float4*)&Bv[4] = *(float4*)&sB[t][4];
    *(float4*)&Bv[8] = *(float4*)&sB[t][8];
    *(float4*)&Bv[12] = *(float4*)&sB[t][12];
#pragma unroll
    for (int n = 0; n < 16; ++n)
      h[n] = fmaf(__expf(dv * An[n]), h[n], du * Bv[n]);
    gi += 1024;
  }
  const size_t so = (((size_t)b * 16 + c) * 1024 + ed) * 16;
  *(float4*)&S[so] = make_float4(h[0], h[1], h[2], h[3]);
  *(float4*)&S[so + 4] = make_float4(h[4], h[5], h[6], h[7]);
  *(float4*)&S[so + 8] = make_float4(h[8], h[9], h[10], h[11]);
  *(float4*)&S[so + 12] = make_float4(h[12], h[13], h[14], h[15]);
  totd[((size_t)b * 16 + c) * 1024 + ed] = cd;
}

// ---------------------------------------------------------------- scan p2
__global__ __launch_bounds__(256) void scan_p2_kernel(
    const float* __restrict__ S, const float* __restrict__ totd,
    const float* __restrict__ A_log, float* __restrict__ HP) {
  int t = blockIdx.x * 256 + threadIdx.x;
  int n = t & 15, ed = (t >> 4) & 1023;
  int b = t >> 14;
  float An = -__expf(A_log[ed * 16 + n]);
  float H = 0.f;
#pragma unroll
  for (int c = 0; c < 16; ++c) {
    size_t i = ((size_t)b * 16 + c) * 1024 + ed;
    HP[i * 16 + n] = H;
    H = fmaf(__expf(An * totd[i]), H, S[i * 16 + n]);
  }
}

// ---------------------------------------------------------------- scan p3
__global__ __launch_bounds__(256) void scan_p3_kernel(
    const unsigned short* __restrict__ dlt, const float* __restrict__ dbc,
    const unsigned short* __restrict__ xc, const float* __restrict__ A_log,
    const float* __restrict__ Dp, const float* __restrict__ HP,
    unsigned short* __restrict__ yg) {
  const int tid = threadIdx.x;
  const int ed = blockIdx.x * 256 + tid;
  const int c = blockIdx.y, b = blockIdx.z;
  const size_t row0 = ((size_t)b << 10) + c * 64;
  __shared__ float sBC[64][32];
  {
    const int w = tid >> 6, l = tid & 63;
    ASYNC_LDS16(&dbc[(row0 + w * 16 + (l >> 3)) * 32 + (l & 7) * 4],
                &sBC[w * 16][0]);
    ASYNC_LDS16(&dbc[(row0 + w * 16 + 8 + (l >> 3)) * 32 + (l & 7) * 4],
                &sBC[w * 16 + 8][0]);
  }
  float An[16], h[16];
  const size_t ho = (((size_t)b * 16 + c) * 1024 + ed) * 16;
#pragma unroll
  for (int n = 0; n < 16; n += 4) {
    float4 a = *(const float4*)&A_log[ed * 16 + n];
    An[n] = -__expf(a.x);
    An[n + 1] = -__expf(a.y);
    An[n + 2] = -__expf(a.z);
    An[n + 3] = -__expf(a.w);
    *(float4*)&h[n] = *(const float4*)&HP[ho + n];
  }
  const float Dv = Dp[ed];
  size_t gi = row0 * 1024 + ed;
  __syncthreads();
  unsigned short nd = dlt[gi], nu = xc[gi], ng = yg[gi];
#pragma unroll 2
  for (int t = 0; t < 64; ++t) {
    float dv = bf2f(nd), u = bf2f(nu), g = bf2f(ng);
    if (t < 63) {
      nd = dlt[gi + 1024];
      nu = xc[gi + 1024];
      ng = yg[gi + 1024];
    }
    float du = dv * u;
    float y = Dv * u;
    float Bv[16], Cv[16];
    *(float4*)&Bv[0] = *(float4*)&sBC[t][0];
    *(float4*)&Bv[4] = *(float4*)&sBC[t][4];
    *(float4*)&Bv[8] = *(float4*)&sBC[t][8];
    *(float4*)&Bv[12] = *(float4*)&sBC[t][12];
    *(float4*)&Cv[0] = *(float4*)&sBC[t][16];
    *(float4*)&Cv[4] = *(float4*)&sBC[t][20];
    *(float4*)&Cv[8] = *(float4*)&sBC[t][24];
    *(float4*)&Cv[12] = *(float4*)&sBC[t][28];
#pragma unroll
    for (int n = 0; n < 16; ++n) {
      h[n] = fmaf(__expf(dv * An[n]), h[n], du * Bv[n]);
      y = fmaf(h[n], Cv[n], y);
    }
    __hip_bfloat16 yb = __float2bfloat16(y * g);
    yg[gi] = *(unsigned short*)&yb;
    gi += 1024;
  }
}

// ---------------------------------------------------------------- head
__global__ __launch_bounds__(256) void head_kernel(
    const float* __restrict__ h, const float* __restrict__ hw,
    const float* __restrict__ hb, float* __restrict__ out) {
  int hc = blockIdx.x * 256 + threadIdx.x;
  int b = blockIdx.y;
  __shared__ float hs[D_];
  for (int d = threadIdx.x; d < D_; d += 256)
    hs[d] = h[((size_t)(b << 10) + 1023) * D_ + d];
  __syncthreads();
  float s = hb[hc];
#pragma unroll 16
  for (int d = 0; d < D_; d += 4) {
    float4 wv = *(const float4*)&hw[(size_t)hc * D_ + d];
    s = fmaf(hs[d], wv.x, s);
    s = fmaf(hs[d + 1], wv.y, s);
    s = fmaf(hs[d + 2], wv.z, s);
    s = fmaf(hs[d + 3], wv.w, s);
  }
  int t = hc >> 5, c = hc & 31;
  out[(size_t)b * 3072 + c * 96 + t] = s;
}

// ---------------------------------------------------------------- launch
extern "C" void kernel_launch(void* const* d_in, const int* in_sizes, int n_in,
                              void* d_out, int out_size, void* d_ws,
                              size_t ws_size, hipStream_t stream) {
  const float* x = (const float*)d_in[0];
  const float* embed_w = (const float*)d_in[1];
  const float* embed_b = (const float*)d_in[2];
  const float* norm_w = (const float*)d_in[3];
  const float* in_proj_w = (const float*)d_in[4];
  const float* conv_w = (const float*)d_in[5];
  const float* conv_b = (const float*)d_in[6];
  const float* x_proj_w = (const float*)d_in[7];
  const float* dt_proj_w = (const float*)d_in[8];
  const float* dt_proj_b = (const float*)d_in[9];
  const float* A_log = (const float*)d_in[10];
  const float* Dp = (const float*)d_in[11];
  const float* out_proj_w = (const float*)d_in[12];
  const float* head_w = (const float*)d_in[13];
  const float* head_b = (const float*)d_in[14];
  float* out = (float*)d_out;

  // fixed: h 33.5MB | wbi 8.39 | wbo 4.19 | wxpT .26 | wdtbf .26 | wcat 10.49
  // per-cb: S cb*1MB + HP cb*1MB + totd cb*64KB
  // rows: hn 1024 | buf1 2048 | buf2 2048 | xcsbf 2048 | dbc 128 = 7296 B
  const size_t fixed0 = 33554432ull + 8388608ull + 4194304ull + 262144ull +
                        262144ull + 10485760ull;
  auto need = [&](int cbx) {
    return fixed0 + (size_t)cbx * (2ull * 1048576 + 65536) +
           (size_t)cbx * 1024 * 7296;
  };
  int cb = 16;
  while (cb > 1 && need(cb) > ws_size) cb >>= 1;
  if (need(cb) > ws_size) return;
  const int Mc = cb * 1024;
  const int nchunks = 16 / cb;

  char* p = (char*)d_ws;
  float* h = (float*)p;                         p += 33554432ull;
  __hip_bfloat16* wbi = (__hip_bfloat16*)p;     p += 8388608ull;
  __hip_bfloat16* wbo = (__hip_bfloat16*)p;     p += 4194304ull;
  __hip_bfloat16* wxpT = (__hip_bfloat16*)p;    p += 262144ull;
  __hip_bfloat16* wdtbf = (__hip_bfloat16*)p;   p += 262144ull;
  __hip_bfloat16* wcat = (__hip_bfloat16*)p;    p += 10485760ull;
  float* S = (float*)p;                         p += (size_t)cb * 1048576;
  float* HP = (float*)p;                        p += (size_t)cb * 1048576;
  float* totd = (float*)p;                      p += (size_t)cb * 65536;
  __hip_bfloat16* hn = (__hip_bfloat16*)p;      p += (size_t)Mc * 1024;
  __hip_bfloat16* buf1 = (__hip_bfloat16*)p;    p += (size_t)Mc * 2048;
  __hip_bfloat16* buf2 = (__hip_bfloat16*)p;    p += (size_t)Mc * 2048;
  __hip_bfloat16* xcsbf = (__hip_bfloat16*)p;   p += (size_t)Mc * 2048;
  float* dbc = (float*)p;

  cvt_bf16_kernel<<<4096, 256, 0, stream>>>(in_proj_w, wbi, 1048576);
  cvt_bf16_kernel<<<2048, 256, 0, stream>>>(out_proj_w, wbo, 524288);
  cvt_bf16_kernel<<<128, 256, 0, stream>>>(dt_proj_w, wdtbf, 32768);
  transpose_xp_kernel<<<512, 256, 0, stream>>>(x_proj_w, wxpT);
  wcat_tail_kernel<<<4096, 256, 0, stream>>>(x_proj_w, wcat);
  // wcat rows 0..1023 = wdt @ wxp[:32]  (1024x1024, K=32)
  for (int i = 0; i < 4; ++i)
    gemm_mfma_kernel<<<dim3(8, 8), 256, 0, stream>>>(
        wdtbf + (size_t)i * 32768, 32, wxpT + (size_t)i * 32768,
        wcat + (size_t)i * 1310720, 1024, 32);
  embed_kernel<<<dim3(16, 16), 256, 0, stream>>>(x, embed_w, embed_b, h);

  for (int i = 0; i < 4; ++i) {
    const float* Ai = A_log + (size_t)i * ED_ * N_;
    for (int ch = 0; ch < nchunks; ++ch) {
      float* hc = h + (size_t)ch * Mc * D_;
      rmsnorm_kernel<<<Mc / 2, 256, 0, stream>>>(hc, norm_w + i * D_, hn);
      // in_proj: col<1024 -> buf1 (xc_raw), col>=1024 -> buf2 (g = silu(z))
      gemm256_kernel<256, 5><<<dim3(8, Mc / 256), 512, 0, stream>>>(
          hn, D_, wbi + (size_t)i * 1048576, nullptr, 0, buf1, buf2, nullptr,
          D_);
      conv_silu_kernel<<<Mc / 2, 256, 0, stream>>>(
          buf1, conv_w + i * ED_ * DC_, conv_b + i * ED_, xcsbf);
      // fused delta+BC (N padded to 1280): delta softplus -> buf1 bf16;
      // B,C f32 -> dbc[row*32+j]
      gemm256_kernel<256, 8><<<dim3(5, Mc / 256), 512, 0, stream>>>(
          xcsbf, ED_, wcat + (size_t)i * 1310720, dbc, 0, buf1, nullptr,
          dt_proj_b + i * ED_, ED_);
      scan_p1_kernel<<<dim3(4, 16, cb), 256, 0, stream>>>(
          (const unsigned short*)buf1, dbc, (const unsigned short*)xcsbf, Ai,
          S, totd);
      scan_p2_kernel<<<cb * 64, 256, 0, stream>>>(S, totd, Ai, HP);
      scan_p3_kernel<<<dim3(4, 16, cb), 256, 0, stream>>>(
          (const unsigned short*)buf1, dbc, (const unsigned short*)xcsbf, Ai,
          Dp + i * ED_, HP, (unsigned short*)buf2);
      // h += y @ out_proj^T
      gemm256_kernel<128, 1><<<dim3(4, Mc / 256), 512, 0, stream>>>(
          buf2, ED_, wbo + (size_t)i * 524288, hc, D_, nullptr, nullptr,
          nullptr, ED_);
    }
  }

  head_kernel<<<dim3(12, B_), 256, 0, stream>>>(h, head_w, head_b, out);
}